// Round 1
// baseline (487.338 us; speedup 1.0000x reference)
//
#include <hip/hip_runtime.h>
#include <math.h>

#define BSZ   2048
#define INDIM 1024
#define QDIM  2048   // HEADS*K_DIM
#define NHT   8      // HEADS*2
#define NKEYS 512
#define HALFD 256
#define KNN   32
#define VDIM  1024
#define HEADS 4

// ---------------- GEMM 1: Q = X @ W^T + b  (2048x2048, K=1024) ----------------
__global__ __launch_bounds__(256) void gemm_q_kernel(
    const float* __restrict__ X, const float* __restrict__ W,
    const float* __restrict__ bq, float* __restrict__ Q) {
  __shared__ __align__(16) float As[16][68];
  __shared__ __align__(16) float Bs[16][68];
  const int tid = threadIdx.x;
  const int tx = tid & 15, ty = tid >> 4;
  const int m0 = blockIdx.y * 64, n0 = blockIdx.x * 64;
  const int lr = tid >> 2;          // 0..63 row in tile
  const int lc = (tid & 3) << 2;    // 0,4,8,12 k in tile
  float acc[4][4] = {};
  for (int kt = 0; kt < INDIM; kt += 16) {
    float4 av = *(const float4*)&X[(size_t)(m0 + lr) * INDIM + kt + lc];
    float4 bv = *(const float4*)&W[(size_t)(n0 + lr) * INDIM + kt + lc];
    __syncthreads();
    As[lc+0][lr] = av.x; As[lc+1][lr] = av.y; As[lc+2][lr] = av.z; As[lc+3][lr] = av.w;
    Bs[lc+0][lr] = bv.x; Bs[lc+1][lr] = bv.y; Bs[lc+2][lr] = bv.z; Bs[lc+3][lr] = bv.w;
    __syncthreads();
    #pragma unroll
    for (int k = 0; k < 16; ++k) {
      float4 a4 = *(const float4*)&As[k][ty << 2];
      float4 b4 = *(const float4*)&Bs[k][tx << 2];
      float aa[4] = {a4.x, a4.y, a4.z, a4.w};
      float bb[4] = {b4.x, b4.y, b4.z, b4.w};
      #pragma unroll
      for (int i = 0; i < 4; ++i)
        #pragma unroll
        for (int j = 0; j < 4; ++j)
          acc[i][j] = fmaf(aa[i], bb[j], acc[i][j]);
    }
  }
  float4 bias = *(const float4*)&bq[n0 + (tx << 2)];
  float bb[4] = {bias.x, bias.y, bias.z, bias.w};
  #pragma unroll
  for (int i = 0; i < 4; ++i) {
    float4 ov;
    ov.x = acc[i][0] + bb[0]; ov.y = acc[i][1] + bb[1];
    ov.z = acc[i][2] + bb[2]; ov.w = acc[i][3] + bb[3];
    *(float4*)&Q[(size_t)(m0 + (ty << 2) + i) * QDIM + n0 + (tx << 2)] = ov;
  }
}

// ------------- GEMM 2: scores[b,ht,n] = sum_d Q[b, ht*256+d] * keys[ht,n,d] -------------
// 8 batched GEMMs: M=2048, N=512, K=256
__global__ __launch_bounds__(256) void gemm_scores_kernel(
    const float* __restrict__ Qm, const float* __restrict__ keys,
    float* __restrict__ S) {
  __shared__ __align__(16) float As[16][68];
  __shared__ __align__(16) float Bs[16][68];
  const int tid = threadIdx.x;
  const int tx = tid & 15, ty = tid >> 4;
  const int ht = blockIdx.z;
  const int m0 = blockIdx.y * 64, n0 = blockIdx.x * 64;
  const int lr = tid >> 2;
  const int lc = (tid & 3) << 2;
  const float* A = Qm + (size_t)ht * HALFD;                 // row stride QDIM
  const float* B = keys + (size_t)ht * NKEYS * HALFD;       // row stride HALFD
  float acc[4][4] = {};
  for (int kt = 0; kt < HALFD; kt += 16) {
    float4 av = *(const float4*)&A[(size_t)(m0 + lr) * QDIM + kt + lc];
    float4 bv = *(const float4*)&B[(size_t)(n0 + lr) * HALFD + kt + lc];
    __syncthreads();
    As[lc+0][lr] = av.x; As[lc+1][lr] = av.y; As[lc+2][lr] = av.z; As[lc+3][lr] = av.w;
    Bs[lc+0][lr] = bv.x; Bs[lc+1][lr] = bv.y; Bs[lc+2][lr] = bv.z; Bs[lc+3][lr] = bv.w;
    __syncthreads();
    #pragma unroll
    for (int k = 0; k < 16; ++k) {
      float4 a4 = *(const float4*)&As[k][ty << 2];
      float4 b4 = *(const float4*)&Bs[k][tx << 2];
      float aa[4] = {a4.x, a4.y, a4.z, a4.w};
      float bb[4] = {b4.x, b4.y, b4.z, b4.w};
      #pragma unroll
      for (int i = 0; i < 4; ++i)
        #pragma unroll
        for (int j = 0; j < 4; ++j)
          acc[i][j] = fmaf(aa[i], bb[j], acc[i][j]);
    }
  }
  #pragma unroll
  for (int i = 0; i < 4; ++i) {
    float4 ov;
    ov.x = acc[i][0]; ov.y = acc[i][1]; ov.z = acc[i][2]; ov.w = acc[i][3];
    // layout: S[(b*8 + ht)*512 + n]
    *(float4*)&S[(size_t)(m0 + (ty << 2) + i) * (NHT * NKEYS) + ht * NKEYS + n0 + (tx << 2)] = ov;
  }
}

// ---------------- top-32 of 512 per row; ties -> smallest index ----------------
__global__ __launch_bounds__(64) void topk1_kernel(
    const float* __restrict__ S, float* __restrict__ sTop, int* __restrict__ iTop) {
  const int row = blockIdx.x;           // b*8 + ht
  const int lane = threadIdx.x;
  const float* sr = S + (size_t)row * NKEYS;
  float v[8];
  #pragma unroll
  for (int j = 0; j < 8; ++j) v[j] = sr[j * 64 + lane];
  for (int r = 0; r < KNN; ++r) {
    float bv = -INFINITY; int bi = 0x7fffffff;
    #pragma unroll
    for (int j = 0; j < 8; ++j) {
      int idx = j * 64 + lane;
      if (v[j] > bv) { bv = v[j]; bi = idx; }
    }
    #pragma unroll
    for (int off = 32; off > 0; off >>= 1) {
      float ov = __shfl_xor(bv, off);
      int oi = __shfl_xor(bi, off);
      if (ov > bv || (ov == bv && oi < bi)) { bv = ov; bi = oi; }
    }
    if (lane == 0) { sTop[(size_t)row * KNN + r] = bv; iTop[(size_t)row * KNN + r] = bi; }
    // predicated removal (avoid runtime register indexing -> scratch)
    const int jj = bi >> 6;
    const bool mine = (bi & 63) == lane;
    #pragma unroll
    for (int j = 0; j < 8; ++j)
      if (mine && j == jj) v[j] = -INFINITY;
  }
}

// ------------- cartesian top-32 of 1024 + per-head softmax -------------
__global__ __launch_bounds__(64) void topk2_kernel(
    const float* __restrict__ sTop, const int* __restrict__ iTop,
    float* __restrict__ wOut, int* __restrict__ idxOut) {
  const int row = blockIdx.x;           // b*4 + h ; stage1 rows 2row, 2row+1
  const int lane = threadIdx.x;
  __shared__ float ls1[32], ls2[32], sel_s[32];
  __shared__ int li1[32], li2[32], sel_i[32];
  if (lane < 32) {
    ls1[lane] = sTop[(size_t)(2 * row) * KNN + lane];
    li1[lane] = iTop[(size_t)(2 * row) * KNN + lane];
    ls2[lane] = sTop[(size_t)(2 * row + 1) * KNN + lane];
    li2[lane] = iTop[(size_t)(2 * row + 1) * KNN + lane];
  }
  __syncthreads();
  float v[16];
  #pragma unroll
  for (int c = 0; c < 16; ++c) {
    int p = c * 64 + lane;
    v[c] = ls1[p >> 5] + ls2[p & 31];
  }
  for (int r = 0; r < KNN; ++r) {
    float bv = -INFINITY; int bp = 0x7fffffff;
    #pragma unroll
    for (int c = 0; c < 16; ++c) {
      int p = c * 64 + lane;
      if (v[c] > bv) { bv = v[c]; bp = p; }
    }
    #pragma unroll
    for (int off = 32; off > 0; off >>= 1) {
      float ov = __shfl_xor(bv, off);
      int op = __shfl_xor(bp, off);
      if (ov > bv || (ov == bv && op < bp)) { bv = ov; bp = op; }
    }
    if (lane == 0) {
      sel_s[r] = bv;
      sel_i[r] = li1[bp >> 5] * NKEYS + li2[bp & 31];
    }
    const int cc = bp >> 6;
    const bool mine = (bp & 63) == lane;
    #pragma unroll
    for (int c = 0; c < 16; ++c)
      if (mine && c == cc) v[c] = -INFINITY;
  }
  __syncthreads();
  const float m = sel_s[0];   // first selected is the max
  float e = (lane < 32) ? expf(sel_s[lane] - m) : 0.0f;
  float s = e;
  #pragma unroll
  for (int off = 32; off > 0; off >>= 1) s += __shfl_xor(s, off);
  if (lane < 32) {
    wOut[(size_t)row * KNN + lane] = e / s;
    idxOut[(size_t)row * KNN + lane] = sel_i[lane];
  }
}

// ---------------- weighted gather: out[b,:] = sum_k w[b,k] * values[idx[b,k],:] ----------------
__global__ __launch_bounds__(256) void gather_kernel(
    const float* __restrict__ values, const float* __restrict__ w,
    const int* __restrict__ idx, float* __restrict__ out) {
  const int b = blockIdx.x;
  const int tid = threadIdx.x;
  __shared__ float lw[128];
  __shared__ int lidx[128];
  if (tid < 128) {
    lw[tid] = w[(size_t)b * 128 + tid];
    lidx[tid] = idx[(size_t)b * 128 + tid];
  }
  __syncthreads();
  const int d0 = tid * 4;
  float4 acc = {0.f, 0.f, 0.f, 0.f};
  #pragma unroll 4
  for (int k = 0; k < 128; ++k) {
    const float4 vv = *(const float4*)&values[(size_t)lidx[k] * VDIM + d0];
    const float ww = lw[k];
    acc.x = fmaf(ww, vv.x, acc.x);
    acc.y = fmaf(ww, vv.y, acc.y);
    acc.z = fmaf(ww, vv.z, acc.z);
    acc.w = fmaf(ww, vv.w, acc.w);
  }
  *(float4*)&out[(size_t)b * VDIM + d0] = acc;
}

extern "C" void kernel_launch(void* const* d_in, const int* in_sizes, int n_in,
                              void* d_out, int out_size, void* d_ws, size_t ws_size,
                              hipStream_t stream) {
  const float* x      = (const float*)d_in[0];
  const float* w_q    = (const float*)d_in[1];
  const float* b_q    = (const float*)d_in[2];
  const float* keys   = (const float*)d_in[3];
  const float* values = (const float*)d_in[4];
  float* out = (float*)d_out;

  char* ws = (char*)d_ws;
  float* Q    = (float*)(ws);                        // 2048*2048*4  = 16 MB
  float* S    = (float*)(ws + (16u << 20));          // 2048*4096*4  = 32 MB
  float* sTop = (float*)(ws + (48u << 20));          // 16384*32*4   = 2 MB
  int*   iTop = (int*)  (ws + (50u << 20));          // 2 MB
  float* wF   = (float*)(ws + (52u << 20));          // 8192*32*4    = 1 MB
  int*   idxF = (int*)  (ws + (53u << 20));          // 1 MB

  gemm_q_kernel<<<dim3(QDIM / 64, BSZ / 64), 256, 0, stream>>>(x, w_q, b_q, Q);
  gemm_scores_kernel<<<dim3(NKEYS / 64, BSZ / 64, NHT), 256, 0, stream>>>(Q, keys, S);
  topk1_kernel<<<BSZ * NHT, 64, 0, stream>>>(S, sTop, iTop);
  topk2_kernel<<<BSZ * HEADS, 64, 0, stream>>>(sTop, iTop, wF, idxF);
  gather_kernel<<<BSZ, 256, 0, stream>>>(values, wF, idxF, out);
}

// Round 2
// 480.687 us; speedup vs baseline: 1.0138x; 1.0138x over previous
//
#include <hip/hip_runtime.h>
#include <math.h>

#define BSZ   2048
#define INDIM 1024
#define QDIM  2048   // HEADS*K_DIM
#define NHT   8      // HEADS*2
#define NKEYS 512
#define HALFD 256
#define KNN   32
#define VDIM  1024
#define HEADS 4

// ---------------- 128x128-tile f32 GEMM:  C[z] = A[z] @ B[z]^T (+bias) ----------------
// 256 threads, 8x8 per-thread acc in split quadrants (+0/+64).
template<bool BIAS>
__global__ __launch_bounds__(256) void gemm128_kernel(
    const float* __restrict__ A, int lda, long aBS,
    const float* __restrict__ B, int ldb, long bBS,
    const float* __restrict__ bias,
    float* __restrict__ C, int ldc, long cBS, int K) {
  __shared__ __align__(16) float As[16][132];
  __shared__ __align__(16) float Bs[16][132];
  const int t = threadIdx.x;
  const int z = blockIdx.z;
  const float* Ab = A + (size_t)z * aBS;
  const float* Bb = B + (size_t)z * bBS;
  const int m0 = blockIdx.y * 128, n0 = blockIdx.x * 128;
  const int r = t >> 2;            // 0..63
  const int c = (t & 3) << 2;      // 0,4,8,12
  const int tx = t & 15, ty = t >> 4;

  // prefetch first k-tile into registers
  float4 a0 = *(const float4*)&Ab[(size_t)(m0 + r) * lda + c];
  float4 a1 = *(const float4*)&Ab[(size_t)(m0 + r + 64) * lda + c];
  float4 b0 = *(const float4*)&Bb[(size_t)(n0 + r) * ldb + c];
  float4 b1 = *(const float4*)&Bb[(size_t)(n0 + r + 64) * ldb + c];

  float acc[8][8] = {};

  for (int kt = 0; kt < K; kt += 16) {
    __syncthreads();   // previous tile's readers done
    As[c + 0][r] = a0.x; As[c + 1][r] = a0.y; As[c + 2][r] = a0.z; As[c + 3][r] = a0.w;
    As[c + 0][r + 64] = a1.x; As[c + 1][r + 64] = a1.y; As[c + 2][r + 64] = a1.z; As[c + 3][r + 64] = a1.w;
    Bs[c + 0][r] = b0.x; Bs[c + 1][r] = b0.y; Bs[c + 2][r] = b0.z; Bs[c + 3][r] = b0.w;
    Bs[c + 0][r + 64] = b1.x; Bs[c + 1][r + 64] = b1.y; Bs[c + 2][r + 64] = b1.z; Bs[c + 3][r + 64] = b1.w;
    __syncthreads();
    if (kt + 16 < K) {   // prefetch next tile (hidden under FMA block)
      a0 = *(const float4*)&Ab[(size_t)(m0 + r) * lda + kt + 16 + c];
      a1 = *(const float4*)&Ab[(size_t)(m0 + r + 64) * lda + kt + 16 + c];
      b0 = *(const float4*)&Bb[(size_t)(n0 + r) * ldb + kt + 16 + c];
      b1 = *(const float4*)&Bb[(size_t)(n0 + r + 64) * ldb + kt + 16 + c];
    }
    #pragma unroll
    for (int k = 0; k < 16; ++k) {
      float4 aL = *(const float4*)&As[k][ty << 2];
      float4 aH = *(const float4*)&As[k][64 + (ty << 2)];
      float4 bL = *(const float4*)&Bs[k][tx << 2];
      float4 bH = *(const float4*)&Bs[k][64 + (tx << 2)];
      float av[8] = {aL.x, aL.y, aL.z, aL.w, aH.x, aH.y, aH.z, aH.w};
      float bv[8] = {bL.x, bL.y, bL.z, bL.w, bH.x, bH.y, bH.z, bH.w};
      #pragma unroll
      for (int i = 0; i < 8; ++i)
        #pragma unroll
        for (int j = 0; j < 8; ++j)
          acc[i][j] = fmaf(av[i], bv[j], acc[i][j]);
    }
  }

  float* Cb = C + (size_t)z * cBS;
  float4 bb0 = {0, 0, 0, 0}, bb1 = {0, 0, 0, 0};
  if (BIAS) {
    bb0 = *(const float4*)&bias[n0 + (tx << 2)];
    bb1 = *(const float4*)&bias[n0 + 64 + (tx << 2)];
  }
  #pragma unroll
  for (int qm = 0; qm < 2; ++qm)
    #pragma unroll
    for (int i = 0; i < 4; ++i) {
      const int row = m0 + qm * 64 + (ty << 2) + i;
      float4 o0, o1;
      o0.x = acc[qm * 4 + i][0] + bb0.x; o0.y = acc[qm * 4 + i][1] + bb0.y;
      o0.z = acc[qm * 4 + i][2] + bb0.z; o0.w = acc[qm * 4 + i][3] + bb0.w;
      o1.x = acc[qm * 4 + i][4] + bb1.x; o1.y = acc[qm * 4 + i][5] + bb1.y;
      o1.z = acc[qm * 4 + i][6] + bb1.z; o1.w = acc[qm * 4 + i][7] + bb1.w;
      *(float4*)&Cb[(size_t)row * ldc + n0 + (tx << 2)] = o0;
      *(float4*)&Cb[(size_t)row * ldc + n0 + 64 + (tx << 2)] = o1;
    }
}

// ---------------- top-32 of 512 per row; ties -> smallest index ----------------
__global__ __launch_bounds__(64) void topk1_kernel(
    const float* __restrict__ S, float* __restrict__ sTop, int* __restrict__ iTop) {
  const int row = blockIdx.x;           // b*8 + ht
  const int lane = threadIdx.x;
  const float* sr = S + (size_t)row * NKEYS;
  float v[8];
  #pragma unroll
  for (int j = 0; j < 8; ++j) v[j] = sr[j * 64 + lane];
  for (int r = 0; r < KNN; ++r) {
    float bv = -INFINITY; int bi = 0x7fffffff;
    #pragma unroll
    for (int j = 0; j < 8; ++j) {
      int idx = j * 64 + lane;
      if (v[j] > bv) { bv = v[j]; bi = idx; }
    }
    #pragma unroll
    for (int off = 32; off > 0; off >>= 1) {
      float ov = __shfl_xor(bv, off);
      int oi = __shfl_xor(bi, off);
      if (ov > bv || (ov == bv && oi < bi)) { bv = ov; bi = oi; }
    }
    if (lane == 0) { sTop[(size_t)row * KNN + r] = bv; iTop[(size_t)row * KNN + r] = bi; }
    const int jj = bi >> 6;
    const bool mine = (bi & 63) == lane;
    #pragma unroll
    for (int j = 0; j < 8; ++j)
      if (mine && j == jj) v[j] = -INFINITY;
  }
}

// ------------- cartesian top-32 of 1024 + per-head softmax -------------
__global__ __launch_bounds__(64) void topk2_kernel(
    const float* __restrict__ sTop, const int* __restrict__ iTop,
    float* __restrict__ wOut, int* __restrict__ idxOut) {
  const int row = blockIdx.x;           // b*4 + h
  const int lane = threadIdx.x;
  __shared__ float ls1[32], ls2[32], sel_s[32];
  __shared__ int li1[32], li2[32], sel_i[32];
  if (lane < 32) {
    ls1[lane] = sTop[(size_t)(2 * row) * KNN + lane];
    li1[lane] = iTop[(size_t)(2 * row) * KNN + lane];
    ls2[lane] = sTop[(size_t)(2 * row + 1) * KNN + lane];
    li2[lane] = iTop[(size_t)(2 * row + 1) * KNN + lane];
  }
  __syncthreads();
  float v[16];
  #pragma unroll
  for (int c = 0; c < 16; ++c) {
    int p = c * 64 + lane;
    v[c] = ls1[p >> 5] + ls2[p & 31];
  }
  for (int r = 0; r < KNN; ++r) {
    float bv = -INFINITY; int bp = 0x7fffffff;
    #pragma unroll
    for (int c = 0; c < 16; ++c) {
      int p = c * 64 + lane;
      if (v[c] > bv) { bv = v[c]; bp = p; }
    }
    #pragma unroll
    for (int off = 32; off > 0; off >>= 1) {
      float ov = __shfl_xor(bv, off);
      int op = __shfl_xor(bp, off);
      if (ov > bv || (ov == bv && op < bp)) { bv = ov; bp = op; }
    }
    if (lane == 0) {
      sel_s[r] = bv;
      sel_i[r] = li1[bp >> 5] * NKEYS + li2[bp & 31];
    }
    const int cc = bp >> 6;
    const bool mine = (bp & 63) == lane;
    #pragma unroll
    for (int c = 0; c < 16; ++c)
      if (mine && c == cc) v[c] = -INFINITY;
  }
  __syncthreads();
  const float m = sel_s[0];
  float e = (lane < 32) ? expf(sel_s[lane] - m) : 0.0f;
  float s = e;
  #pragma unroll
  for (int off = 32; off > 0; off >>= 1) s += __shfl_xor(s, off);
  if (lane < 32) {
    wOut[(size_t)row * KNN + lane] = e / s;
    idxOut[(size_t)row * KNN + lane] = sel_i[lane];
  }
}

// ---------------- weighted gather: out[b,:] = sum_k w[b,k] * values[idx[b,k],:] ----------------
__global__ __launch_bounds__(256) void gather_kernel(
    const float* __restrict__ values, const float* __restrict__ w,
    const int* __restrict__ idx, float* __restrict__ out) {
  const int b = blockIdx.x;
  const int tid = threadIdx.x;
  __shared__ float lw[128];
  __shared__ int lidx[128];
  if (tid < 128) {
    lw[tid] = w[(size_t)b * 128 + tid];
    lidx[tid] = idx[(size_t)b * 128 + tid];
  }
  __syncthreads();
  const int d0 = tid * 4;
  float4 acc = {0.f, 0.f, 0.f, 0.f};
  #pragma unroll 4
  for (int k = 0; k < 128; ++k) {
    const float4 vv = *(const float4*)&values[(size_t)lidx[k] * VDIM + d0];
    const float ww = lw[k];
    acc.x = fmaf(ww, vv.x, acc.x);
    acc.y = fmaf(ww, vv.y, acc.y);
    acc.z = fmaf(ww, vv.z, acc.z);
    acc.w = fmaf(ww, vv.w, acc.w);
  }
  *(float4*)&out[(size_t)b * VDIM + d0] = acc;
}

extern "C" void kernel_launch(void* const* d_in, const int* in_sizes, int n_in,
                              void* d_out, int out_size, void* d_ws, size_t ws_size,
                              hipStream_t stream) {
  const float* x      = (const float*)d_in[0];
  const float* w_q    = (const float*)d_in[1];
  const float* b_q    = (const float*)d_in[2];
  const float* keys   = (const float*)d_in[3];
  const float* values = (const float*)d_in[4];
  float* out = (float*)d_out;

  char* ws = (char*)d_ws;
  float* Q    = (float*)(ws);                        // 2048*2048*4  = 16 MB
  float* S    = (float*)(ws + (16u << 20));          // 2048*4096*4  = 32 MB
  float* sTop = (float*)(ws + (48u << 20));          // 16384*32*4   = 2 MB
  int*   iTop = (int*)  (ws + (50u << 20));          // 2 MB
  float* wF   = (float*)(ws + (52u << 20));          // 8192*32*4    = 1 MB
  int*   idxF = (int*)  (ws + (53u << 20));          // 1 MB

  // Q = X @ W^T + b : M=2048, N=2048, K=1024
  gemm128_kernel<true><<<dim3(QDIM / 128, BSZ / 128, 1), 256, 0, stream>>>(
      x, INDIM, 0, w_q, INDIM, 0, b_q, Q, QDIM, 0, INDIM);
  // scores[b,ht,n] : 8 batched GEMMs M=2048, N=512, K=256
  gemm128_kernel<false><<<dim3(NKEYS / 128, BSZ / 128, NHT), 256, 0, stream>>>(
      Q, QDIM, HALFD, keys, HALFD, (long)NKEYS * HALFD, nullptr,
      S, NHT * NKEYS, NKEYS, HALFD);
  topk1_kernel<<<BSZ * NHT, 64, 0, stream>>>(S, sTop, iTop);
  topk2_kernel<<<BSZ * HEADS, 64, 0, stream>>>(sTop, iTop, wF, idxF);
  gather_kernel<<<BSZ, 256, 0, stream>>>(values, wF, idxF, out);
}

// Round 3
// 439.526 us; speedup vs baseline: 1.1088x; 1.0936x over previous
//
#include <hip/hip_runtime.h>
#include <math.h>

#define BSZ   2048
#define INDIM 1024
#define QDIM  2048   // HEADS*K_DIM
#define NHT   8      // HEADS*2
#define NKEYS 512
#define HALFD 256
#define KNN   32
#define VDIM  1024
#define HEADS 4

typedef _Float16 v8h __attribute__((ext_vector_type(8)));
typedef _Float16 v4h __attribute__((ext_vector_type(4)));
typedef float    v4f __attribute__((ext_vector_type(4)));

// ---------- f32 -> {h, h/64, m=64*(a-h)} f16 plane split ----------
// A-side plane order: [h, h/64, m]; B-side: [h, m, h/64]
template<int KSHIFT, bool ASIDE>
__global__ __launch_bounds__(256) void split_kernel(
    const float* __restrict__ in, _Float16* __restrict__ out, int total4) {
  const int i = blockIdx.x * 256 + threadIdx.x;
  if (i >= total4) return;
  const long e0 = (long)i * 4;
  const int K = 1 << KSHIFT;
  const long r = e0 >> KSHIFT;
  const int k = (int)(e0 & (K - 1));
  const float4 a = *(const float4*)&in[e0];
  const float av[4] = {a.x, a.y, a.z, a.w};
  v4h hv, dv, mv;
  #pragma unroll
  for (int u = 0; u < 4; ++u) {
    const _Float16 hh = (_Float16)av[u];
    hv[u] = hh;
    mv[u] = (_Float16)((av[u] - (float)hh) * 64.0f);
    dv[u] = (_Float16)((float)hh * 0.015625f);
  }
  _Float16* base = out + r * (3L * K) + k;
  *(v4h*)(base)         = hv;
  *(v4h*)(base + K)     = ASIDE ? dv : mv;
  *(v4h*)(base + 2 * K) = ASIDE ? mv : dv;
}

// ---------- async global->LDS 16B ----------
__device__ __forceinline__ void gload16(const _Float16* g, _Float16* l) {
  __builtin_amdgcn_global_load_lds(
      (const __attribute__((address_space(1))) unsigned int*)g,
      (__attribute__((address_space(3))) unsigned int*)l, 16, 0, 0);
}

// ---------- f16 MFMA GEMM, 128x128 tile, BK=32, C = A @ B^T ----------
// Both A,B row-major with K' contiguous. Q_EPI: bias + split-plane epilogue.
template<bool Q_EPI>
__global__ __launch_bounds__(256) void mfma_gemm(
    const _Float16* __restrict__ A, int lda, long aBS,
    const _Float16* __restrict__ B, int ldb, long bBS,
    const float* __restrict__ bias,
    float* __restrict__ Cf, int ldc, long cBS,
    _Float16* __restrict__ Cq, int K) {
  __shared__ _Float16 Asm[128 * 32];
  __shared__ _Float16 Bsm[128 * 32];
  const int t = threadIdx.x;
  const int z = blockIdx.z;
  const _Float16* Ab = A + (size_t)z * aBS;
  const _Float16* Bb = B + (size_t)z * bBS;
  const int m0 = blockIdx.y * 128, n0 = blockIdx.x * 128;

  // staging: LDS dest linear (o = t*16 [+4096]); global source inverse-swizzled
  // swizzle: byte ^= ((byte>>7)&3)<<4   (spreads row-major [128][64B] banks)
  const int o0 = t * 16;
  const int os = o0 ^ (((o0 >> 7) & 3) << 4);
  const int sr = os >> 6;            // source row within tile (0..63)
  const int sk = (os & 63) >> 1;     // source k element (0..31)
  const _Float16* gA0 = Ab + (size_t)(m0 + sr) * lda + sk;
  const _Float16* gA1 = Ab + (size_t)(m0 + sr + 64) * lda + sk;
  const _Float16* gB0 = Bb + (size_t)(n0 + sr) * ldb + sk;
  const _Float16* gB1 = Bb + (size_t)(n0 + sr + 64) * ldb + sk;
  _Float16* lA0 = Asm + t * 8;
  _Float16* lA1 = Asm + t * 8 + 2048;
  _Float16* lB0 = Bsm + t * 8;
  _Float16* lB1 = Bsm + t * 8 + 2048;

  const int lane = t & 63, w = t >> 6;
  const int wr = (w >> 1) * 64, wc = (w & 1) * 64;
  const int fr = lane & 15, kg = lane >> 4;

  int aoff[4], boff[4];
  #pragma unroll
  for (int i = 0; i < 4; ++i) {
    const int ra = wr + i * 16 + fr;
    aoff[i] = (ra * 64 + ((kg ^ ((ra >> 1) & 3)) * 16)) >> 1;
    const int rb = wc + i * 16 + fr;
    boff[i] = (rb * 64 + ((kg ^ ((rb >> 1) & 3)) * 16)) >> 1;
  }

  v4f acc[4][4];
  #pragma unroll
  for (int i = 0; i < 4; ++i)
    #pragma unroll
    for (int j = 0; j < 4; ++j)
      acc[i][j] = (v4f){0.f, 0.f, 0.f, 0.f};

  for (int kt = 0; kt < K; kt += 32) {
    __syncthreads();                 // previous tile's readers done
    gload16(gA0 + kt, lA0);
    gload16(gA1 + kt, lA1);
    gload16(gB0 + kt, lB0);
    gload16(gB1 + kt, lB1);
    __syncthreads();                 // drains vmcnt -> LDS ready
    v8h af[4], bf[4];
    #pragma unroll
    for (int i = 0; i < 4; ++i) af[i] = *(const v8h*)(Asm + aoff[i]);
    #pragma unroll
    for (int j = 0; j < 4; ++j) bf[j] = *(const v8h*)(Bsm + boff[j]);
    #pragma unroll
    for (int i = 0; i < 4; ++i)
      #pragma unroll
      for (int j = 0; j < 4; ++j)
        acc[i][j] = __builtin_amdgcn_mfma_f32_16x16x32_f16(af[i], bf[j], acc[i][j], 0, 0, 0);
  }

  // C/D map (16x16x32, dtype-independent): col = lane&15, row = (lane>>4)*4 + reg
  if (Q_EPI) {
    #pragma unroll
    for (int j = 0; j < 4; ++j) {
      const int col = n0 + wc + j * 16 + fr;     // 0..2047
      const float bv = bias[col];
      const int ht = col >> 8, d = col & 255;
      #pragma unroll
      for (int i = 0; i < 4; ++i)
        #pragma unroll
        for (int rr = 0; rr < 4; ++rr) {
          const int rowg = m0 + wr + i * 16 + kg * 4 + rr;
          const float val = acc[i][j][rr] + bv;
          const _Float16 hh = (_Float16)val;
          const _Float16 mm = (_Float16)((val - (float)hh) * 64.0f);
          const _Float16 hd = (_Float16)((float)hh * 0.015625f);
          _Float16* p = Cq + (size_t)rowg * (3 * HALFD * NHT) + ht * (3 * HALFD) + d;
          p[0] = hh; p[HALFD] = hd; p[2 * HALFD] = mm;   // A-side order [h, h/64, m]
        }
    }
  } else {
    float* Cb = Cf + (size_t)z * cBS;
    #pragma unroll
    for (int i = 0; i < 4; ++i)
      #pragma unroll
      for (int j = 0; j < 4; ++j)
        #pragma unroll
        for (int rr = 0; rr < 4; ++rr) {
          const int rowg = m0 + wr + i * 16 + kg * 4 + rr;
          const int colg = n0 + wc + j * 16 + fr;
          Cb[(size_t)rowg * ldc + colg] = acc[i][j][rr];
        }
  }
}

// ---------------- top-32 of 512 per row; ties -> smallest index ----------------
__global__ __launch_bounds__(64) void topk1_kernel(
    const float* __restrict__ S, float* __restrict__ sTop, int* __restrict__ iTop) {
  const int row = blockIdx.x;           // b*8 + ht
  const int lane = threadIdx.x;
  const float* sr = S + (size_t)row * NKEYS;
  float v[8];
  #pragma unroll
  for (int j = 0; j < 8; ++j) v[j] = sr[j * 64 + lane];
  for (int r = 0; r < KNN; ++r) {
    float bv = -INFINITY; int bi = 0x7fffffff;
    #pragma unroll
    for (int j = 0; j < 8; ++j) {
      int idx = j * 64 + lane;
      if (v[j] > bv) { bv = v[j]; bi = idx; }
    }
    #pragma unroll
    for (int off = 32; off > 0; off >>= 1) {
      float ov = __shfl_xor(bv, off);
      int oi = __shfl_xor(bi, off);
      if (ov > bv || (ov == bv && oi < bi)) { bv = ov; bi = oi; }
    }
    if (lane == 0) { sTop[(size_t)row * KNN + r] = bv; iTop[(size_t)row * KNN + r] = bi; }
    const int jj = bi >> 6;
    const bool mine = (bi & 63) == lane;
    #pragma unroll
    for (int j = 0; j < 8; ++j)
      if (mine && j == jj) v[j] = -INFINITY;
  }
}

// ------------- cartesian top-32 of 1024 + per-head softmax -------------
__global__ __launch_bounds__(64) void topk2_kernel(
    const float* __restrict__ sTop, const int* __restrict__ iTop,
    float* __restrict__ wOut, int* __restrict__ idxOut) {
  const int row = blockIdx.x;           // b*4 + h
  const int lane = threadIdx.x;
  __shared__ float ls1[32], ls2[32], sel_s[32];
  __shared__ int li1[32], li2[32], sel_i[32];
  if (lane < 32) {
    ls1[lane] = sTop[(size_t)(2 * row) * KNN + lane];
    li1[lane] = iTop[(size_t)(2 * row) * KNN + lane];
    ls2[lane] = sTop[(size_t)(2 * row + 1) * KNN + lane];
    li2[lane] = iTop[(size_t)(2 * row + 1) * KNN + lane];
  }
  __syncthreads();
  float v[16];
  #pragma unroll
  for (int c = 0; c < 16; ++c) {
    int p = c * 64 + lane;
    v[c] = ls1[p >> 5] + ls2[p & 31];
  }
  for (int r = 0; r < KNN; ++r) {
    float bv = -INFINITY; int bp = 0x7fffffff;
    #pragma unroll
    for (int c = 0; c < 16; ++c) {
      int p = c * 64 + lane;
      if (v[c] > bv) { bv = v[c]; bp = p; }
    }
    #pragma unroll
    for (int off = 32; off > 0; off >>= 1) {
      float ov = __shfl_xor(bv, off);
      int op = __shfl_xor(bp, off);
      if (ov > bv || (ov == bv && op < bp)) { bv = ov; bp = op; }
    }
    if (lane == 0) {
      sel_s[r] = bv;
      sel_i[r] = li1[bp >> 5] * NKEYS + li2[bp & 31];
    }
    const int cc = bp >> 6;
    const bool mine = (bp & 63) == lane;
    #pragma unroll
    for (int c = 0; c < 16; ++c)
      if (mine && c == cc) v[c] = -INFINITY;
  }
  __syncthreads();
  const float m = sel_s[0];
  float e = (lane < 32) ? expf(sel_s[lane] - m) : 0.0f;
  float s = e;
  #pragma unroll
  for (int off = 32; off > 0; off >>= 1) s += __shfl_xor(s, off);
  if (lane < 32) {
    wOut[(size_t)row * KNN + lane] = e / s;
    idxOut[(size_t)row * KNN + lane] = sel_i[lane];
  }
}

// ---------------- weighted gather ----------------
__global__ __launch_bounds__(256) void gather_kernel(
    const float* __restrict__ values, const float* __restrict__ w,
    const int* __restrict__ idx, float* __restrict__ out) {
  const int b = blockIdx.x;
  const int tid = threadIdx.x;
  __shared__ float lw[128];
  __shared__ int lidx[128];
  if (tid < 128) {
    lw[tid] = w[(size_t)b * 128 + tid];
    lidx[tid] = idx[(size_t)b * 128 + tid];
  }
  __syncthreads();
  const int d0 = tid * 4;
  float4 acc = {0.f, 0.f, 0.f, 0.f};
  #pragma unroll 4
  for (int k = 0; k < 128; ++k) {
    const float4 vv = *(const float4*)&values[(size_t)lidx[k] * VDIM + d0];
    const float ww = lw[k];
    acc.x = fmaf(ww, vv.x, acc.x);
    acc.y = fmaf(ww, vv.y, acc.y);
    acc.z = fmaf(ww, vv.z, acc.z);
    acc.w = fmaf(ww, vv.w, acc.w);
  }
  *(float4*)&out[(size_t)b * VDIM + d0] = acc;
}

extern "C" void kernel_launch(void* const* d_in, const int* in_sizes, int n_in,
                              void* d_out, int out_size, void* d_ws, size_t ws_size,
                              hipStream_t stream) {
  const float* x      = (const float*)d_in[0];
  const float* w_q    = (const float*)d_in[1];
  const float* b_q    = (const float*)d_in[2];
  const float* keys   = (const float*)d_in[3];
  const float* values = (const float*)d_in[4];
  float* out = (float*)d_out;

  char* ws = (char*)d_ws;
  _Float16* xs    = (_Float16*)(ws);                  // 2048*3072*2 = 12.6 MB
  _Float16* wqs   = (_Float16*)(ws + (16u  << 20));   // 12.6 MB
  _Float16* keyss = (_Float16*)(ws + (32u  << 20));   // 8*512*768*2 = 6.3 MB
  _Float16* Qs    = (_Float16*)(ws + (40u  << 20));   // 2048*6144*2 = 25.2 MB
  float*    S     = (float*)   (ws + (68u  << 20));   // 2048*4096*4 = 32 MB
  float*    sTop  = (float*)   (ws + (100u << 20));   // 2 MB
  int*      iTop  = (int*)     (ws + (102u << 20));   // 2 MB
  float*    wF    = (float*)   (ws + (104u << 20));   // 1 MB
  int*      idxF  = (int*)     (ws + (105u << 20));   // 1 MB

  // plane splits
  split_kernel<10, true ><<<2048, 256, 0, stream>>>(x,    xs,    524288);
  split_kernel<10, false><<<2048, 256, 0, stream>>>(w_q,  wqs,   524288);
  split_kernel<8,  false><<<1024, 256, 0, stream>>>(keys, keyss, 262144);

  // GEMM1: Q'' = split(x'' @ w_q''^T + b) : M=2048, N=2048, K'=3072
  mfma_gemm<true><<<dim3(QDIM / 128, BSZ / 128, 1), 256, 0, stream>>>(
      xs, 3 * INDIM, 0, wqs, 3 * INDIM, 0, b_q,
      nullptr, 0, 0, Qs, 3 * INDIM);
  // GEMM2: S = Q'' @ keys''^T : 8 x (M=2048, N=512, K'=768)
  mfma_gemm<false><<<dim3(NKEYS / 128, BSZ / 128, NHT), 256, 0, stream>>>(
      Qs, 3 * HALFD * NHT, 3 * HALFD, keyss, 3 * HALFD, (long)NKEYS * 3 * HALFD, nullptr,
      S, NHT * NKEYS, NKEYS, nullptr, 3 * HALFD);

  topk1_kernel<<<BSZ * NHT, 64, 0, stream>>>(S, sTop, iTop);
  topk2_kernel<<<BSZ * HEADS, 64, 0, stream>>>(sTop, iTop, wF, idxF);
  gather_kernel<<<BSZ, 256, 0, stream>>>(values, wF, idxF, out);
}

// Round 4
// 412.635 us; speedup vs baseline: 1.1810x; 1.0652x over previous
//
#include <hip/hip_runtime.h>
#include <math.h>

#define BSZ   2048
#define INDIM 1024
#define QDIM  2048   // HEADS*K_DIM
#define NHT   8      // HEADS*2
#define NKEYS 512
#define HALFD 256
#define KNN   32
#define VDIM  1024
#define HEADS 4

typedef _Float16 v8h __attribute__((ext_vector_type(8)));
typedef _Float16 v4h __attribute__((ext_vector_type(4)));
typedef float    v4f __attribute__((ext_vector_type(4)));

// ---------- f32 -> {h, h/64, m=64*(a-h)} f16 plane split ----------
// A-side plane order: [h, h/64, m]; B-side: [h, m, h/64]
template<int KSHIFT, bool ASIDE>
__global__ __launch_bounds__(256) void split_kernel(
    const float* __restrict__ in, _Float16* __restrict__ out, int total4) {
  const int i = blockIdx.x * 256 + threadIdx.x;
  if (i >= total4) return;
  const long e0 = (long)i * 4;
  const int K = 1 << KSHIFT;
  const long r = e0 >> KSHIFT;
  const int k = (int)(e0 & (K - 1));
  const float4 a = *(const float4*)&in[e0];
  const float av[4] = {a.x, a.y, a.z, a.w};
  v4h hv, dv, mv;
  #pragma unroll
  for (int u = 0; u < 4; ++u) {
    const _Float16 hh = (_Float16)av[u];
    hv[u] = hh;
    mv[u] = (_Float16)((av[u] - (float)hh) * 64.0f);
    dv[u] = (_Float16)((float)hh * 0.015625f);
  }
  _Float16* base = out + r * (3L * K) + k;
  *(v4h*)(base)         = hv;
  *(v4h*)(base + K)     = ASIDE ? dv : mv;
  *(v4h*)(base + 2 * K) = ASIDE ? mv : dv;
}

// ---------- async global->LDS 16B ----------
__device__ __forceinline__ void gload16(const _Float16* g, _Float16* l) {
  __builtin_amdgcn_global_load_lds(
      (const __attribute__((address_space(1))) unsigned int*)g,
      (__attribute__((address_space(3))) unsigned int*)l, 16, 0, 0);
}

// ---------- f16 MFMA GEMM, 128x128 tile, BK=32, 2-phase dbuf, C = A @ B^T ----------
// Q_EPI: bias + 3-plane f16 epilogue (LDS-transposed, vectorized stores).
template<bool Q_EPI>
__global__ __launch_bounds__(256) void mfma_gemm(
    const _Float16* __restrict__ A, int lda, long aBS,
    const _Float16* __restrict__ B, int ldb, long bBS,
    const float* __restrict__ bias,
    float* __restrict__ Cf, int ldc, long cBS,
    _Float16* __restrict__ Cq, int K) {
  extern __shared__ __align__(16) char smem[];
  _Float16* Asm = (_Float16*)smem;             // [2][4096] f16 = 16 KB
  _Float16* Bsm = (_Float16*)(smem + 16384);   // [2][4096] f16 = 16 KB
  const int t = threadIdx.x;
  const int z = blockIdx.z;
  const _Float16* Ab = A + (size_t)z * aBS;
  const _Float16* Bb = B + (size_t)z * bBS;
  const int m0 = blockIdx.y * 128, n0 = blockIdx.x * 128;

  // staging: LDS dest linear (t*16 B within 4KB half); global source inverse-swizzled
  // swizzle: byte ^= ((byte>>7)&3)<<4
  const int o0 = t * 16;
  const int os = o0 ^ (((o0 >> 7) & 3) << 4);
  const int sr = os >> 6;            // source row within 64-row half
  const int sk = (os & 63) >> 1;     // source k element (0..31)
  const _Float16* gA0 = Ab + (size_t)(m0 + sr) * lda + sk;
  const _Float16* gA1 = Ab + (size_t)(m0 + sr + 64) * lda + sk;
  const _Float16* gB0 = Bb + (size_t)(n0 + sr) * ldb + sk;
  const _Float16* gB1 = Bb + (size_t)(n0 + sr + 64) * ldb + sk;

  const int lane = t & 63, w = t >> 6;
  const int wr = (w >> 1) * 64, wc = (w & 1) * 64;
  const int fr = lane & 15, kg = lane >> 4;

  int aoff[4], boff[4];
  #pragma unroll
  for (int i = 0; i < 4; ++i) {
    const int ra = wr + i * 16 + fr;
    aoff[i] = (ra * 64 + ((kg ^ ((ra >> 1) & 3)) * 16)) >> 1;
    const int rb = wc + i * 16 + fr;
    boff[i] = (rb * 64 + ((kg ^ ((rb >> 1) & 3)) * 16)) >> 1;
  }

  v4f acc[4][4];
  #pragma unroll
  for (int i = 0; i < 4; ++i)
    #pragma unroll
    for (int j = 0; j < 4; ++j)
      acc[i][j] = (v4f){0.f, 0.f, 0.f, 0.f};

  // prologue: stage tile 0 into buf 0
  gload16(gA0, Asm + t * 8);
  gload16(gA1, Asm + 2048 + t * 8);
  gload16(gB0, Bsm + t * 8);
  gload16(gB1, Bsm + 2048 + t * 8);
  __syncthreads();

  int cur = 0;
  for (int kt = 0; kt < K; kt += 32) {
    const int nxt = cur ^ 1;
    if (kt + 32 < K) {   // issue next-tile loads FIRST (overlap with compute)
      gload16(gA0 + kt + 32, Asm + nxt * 4096 + t * 8);
      gload16(gA1 + kt + 32, Asm + nxt * 4096 + 2048 + t * 8);
      gload16(gB0 + kt + 32, Bsm + nxt * 4096 + t * 8);
      gload16(gB1 + kt + 32, Bsm + nxt * 4096 + 2048 + t * 8);
    }
    v8h af[4], bf[4];
    #pragma unroll
    for (int i = 0; i < 4; ++i) af[i] = *(const v8h*)(Asm + cur * 4096 + aoff[i]);
    #pragma unroll
    for (int j = 0; j < 4; ++j) bf[j] = *(const v8h*)(Bsm + cur * 4096 + boff[j]);
    #pragma unroll
    for (int i = 0; i < 4; ++i)
      #pragma unroll
      for (int j = 0; j < 4; ++j)
        acc[i][j] = __builtin_amdgcn_mfma_f32_16x16x32_f16(af[i], bf[j], acc[i][j], 0, 0, 0);
    __syncthreads();   // next tile landed; readers done before overwrite
    cur = nxt;
  }

  // C/D map (16x16x32): col = lane&15, row = (lane>>4)*4 + reg
  if (Q_EPI) {
    // two 64-col passes through LDS [128][68] f32 (34816 B)
    float* Ct = (float*)smem;
    #pragma unroll
    for (int half = 0; half < 2; ++half) {
      __syncthreads();
      if ((w & 1) == half) {
        #pragma unroll
        for (int j = 0; j < 4; ++j) {
          const int colq = j * 16 + fr;          // 0..63 within half
          const float bv = bias[n0 + half * 64 + colq];
          #pragma unroll
          for (int i = 0; i < 4; ++i)
            #pragma unroll
            for (int rr = 0; rr < 4; ++rr)
              Ct[(wr + i * 16 + kg * 4 + rr) * 68 + colq] = acc[i][j][rr] + bv;
        }
      }
      __syncthreads();
      const int r = t >> 1, cb = (t & 1) * 32;
      const int gcol = n0 + half * 64 + cb;      // 32-aligned
      const int ht = gcol >> 8, dd = gcol & 255;
      _Float16* p = Cq + (size_t)(m0 + r) * (3 * HALFD * NHT) + ht * (3 * HALFD) + dd;
      #pragma unroll
      for (int u = 0; u < 32; u += 8) {
        float vv[8];
        *(float4*)&vv[0] = *(const float4*)&Ct[r * 68 + cb + u];
        *(float4*)&vv[4] = *(const float4*)&Ct[r * 68 + cb + u + 4];
        v8h hv, dv, mv;
        #pragma unroll
        for (int e = 0; e < 8; ++e) {
          const _Float16 hh = (_Float16)vv[e];
          hv[e] = hh;
          mv[e] = (_Float16)((vv[e] - (float)hh) * 64.0f);
          dv[e] = (_Float16)((float)hh * 0.015625f);
        }
        *(v8h*)(p + u) = hv;                    // h
        *(v8h*)(p + HALFD + u) = dv;            // h/64
        *(v8h*)(p + 2 * HALFD + u) = mv;        // m
      }
    }
  } else {
    float* Cb = Cf + (size_t)z * cBS;
    #pragma unroll
    for (int i = 0; i < 4; ++i)
      #pragma unroll
      for (int j = 0; j < 4; ++j)
        #pragma unroll
        for (int rr = 0; rr < 4; ++rr) {
          const int rowg = m0 + wr + i * 16 + kg * 4 + rr;
          const int colg = n0 + wc + j * 16 + fr;
          Cb[(size_t)rowg * ldc + colg] = acc[i][j][rr];
        }
  }
}

// ---------------- top-32 of 512 per row; ties -> smallest index ----------------
__global__ __launch_bounds__(64) void topk1_kernel(
    const float* __restrict__ S, float* __restrict__ sTop, int* __restrict__ iTop) {
  const int row = blockIdx.x;           // b*8 + ht
  const int lane = threadIdx.x;
  const float* sr = S + (size_t)row * NKEYS;
  float v[8];
  #pragma unroll
  for (int j = 0; j < 8; ++j) v[j] = sr[j * 64 + lane];
  for (int r = 0; r < KNN; ++r) {
    float bv = -INFINITY; int bi = 0x7fffffff;
    #pragma unroll
    for (int j = 0; j < 8; ++j) {
      int idx = j * 64 + lane;
      if (v[j] > bv) { bv = v[j]; bi = idx; }
    }
    #pragma unroll
    for (int off = 32; off > 0; off >>= 1) {
      float ov = __shfl_xor(bv, off);
      int oi = __shfl_xor(bi, off);
      if (ov > bv || (ov == bv && oi < bi)) { bv = ov; bi = oi; }
    }
    if (lane == 0) { sTop[(size_t)row * KNN + r] = bv; iTop[(size_t)row * KNN + r] = bi; }
    const int jj = bi >> 6;
    const bool mine = (bi & 63) == lane;
    #pragma unroll
    for (int j = 0; j < 8; ++j)
      if (mine && j == jj) v[j] = -INFINITY;
  }
}

// ------------- cartesian top-32 of 1024 + per-head softmax -------------
__global__ __launch_bounds__(64) void topk2_kernel(
    const float* __restrict__ sTop, const int* __restrict__ iTop,
    float* __restrict__ wOut, int* __restrict__ idxOut) {
  const int row = blockIdx.x;           // b*4 + h
  const int lane = threadIdx.x;
  __shared__ float ls1[32], ls2[32], sel_s[32];
  __shared__ int li1[32], li2[32], sel_i[32];
  if (lane < 32) {
    ls1[lane] = sTop[(size_t)(2 * row) * KNN + lane];
    li1[lane] = iTop[(size_t)(2 * row) * KNN + lane];
    ls2[lane] = sTop[(size_t)(2 * row + 1) * KNN + lane];
    li2[lane] = iTop[(size_t)(2 * row + 1) * KNN + lane];
  }
  __syncthreads();
  float v[16];
  #pragma unroll
  for (int c = 0; c < 16; ++c) {
    int p = c * 64 + lane;
    v[c] = ls1[p >> 5] + ls2[p & 31];
  }
  for (int r = 0; r < KNN; ++r) {
    float bv = -INFINITY; int bp = 0x7fffffff;
    #pragma unroll
    for (int c = 0; c < 16; ++c) {
      int p = c * 64 + lane;
      if (v[c] > bv) { bv = v[c]; bp = p; }
    }
    #pragma unroll
    for (int off = 32; off > 0; off >>= 1) {
      float ov = __shfl_xor(bv, off);
      int op = __shfl_xor(bp, off);
      if (ov > bv || (ov == bv && op < bp)) { bv = ov; bp = op; }
    }
    if (lane == 0) {
      sel_s[r] = bv;
      sel_i[r] = li1[bp >> 5] * NKEYS + li2[bp & 31];
    }
    const int cc = bp >> 6;
    const bool mine = (bp & 63) == lane;
    #pragma unroll
    for (int c = 0; c < 16; ++c)
      if (mine && c == cc) v[c] = -INFINITY;
  }
  __syncthreads();
  const float m = sel_s[0];
  float e = (lane < 32) ? expf(sel_s[lane] - m) : 0.0f;
  float s = e;
  #pragma unroll
  for (int off = 32; off > 0; off >>= 1) s += __shfl_xor(s, off);
  if (lane < 32) {
    wOut[(size_t)row * KNN + lane] = e / s;
    idxOut[(size_t)row * KNN + lane] = sel_i[lane];
  }
}

// ---------------- weighted gather ----------------
__global__ __launch_bounds__(256) void gather_kernel(
    const float* __restrict__ values, const float* __restrict__ w,
    const int* __restrict__ idx, float* __restrict__ out) {
  const int b = blockIdx.x;
  const int tid = threadIdx.x;
  __shared__ float lw[128];
  __shared__ int lidx[128];
  if (tid < 128) {
    lw[tid] = w[(size_t)b * 128 + tid];
    lidx[tid] = idx[(size_t)b * 128 + tid];
  }
  __syncthreads();
  const int d0 = tid * 4;
  float4 acc = {0.f, 0.f, 0.f, 0.f};
  #pragma unroll 8
  for (int k = 0; k < 128; ++k) {
    const float4 vv = *(const float4*)&values[(size_t)lidx[k] * VDIM + d0];
    const float ww = lw[k];
    acc.x = fmaf(ww, vv.x, acc.x);
    acc.y = fmaf(ww, vv.y, acc.y);
    acc.z = fmaf(ww, vv.z, acc.z);
    acc.w = fmaf(ww, vv.w, acc.w);
  }
  *(float4*)&out[(size_t)b * VDIM + d0] = acc;
}

extern "C" void kernel_launch(void* const* d_in, const int* in_sizes, int n_in,
                              void* d_out, int out_size, void* d_ws, size_t ws_size,
                              hipStream_t stream) {
  const float* x      = (const float*)d_in[0];
  const float* w_q    = (const float*)d_in[1];
  const float* b_q    = (const float*)d_in[2];
  const float* keys   = (const float*)d_in[3];
  const float* values = (const float*)d_in[4];
  float* out = (float*)d_out;

  char* ws = (char*)d_ws;
  _Float16* xs    = (_Float16*)(ws);                  // 2048*3072*2 = 12.6 MB
  _Float16* wqs   = (_Float16*)(ws + (16u  << 20));   // 12.6 MB
  _Float16* keyss = (_Float16*)(ws + (32u  << 20));   // 8*512*768*2 = 6.3 MB
  _Float16* Qs    = (_Float16*)(ws + (40u  << 20));   // 2048*6144*2 = 25.2 MB
  float*    S     = (float*)   (ws + (68u  << 20));   // 2048*4096*4 = 32 MB
  float*    sTop  = (float*)   (ws + (100u << 20));   // 2 MB
  int*      iTop  = (int*)     (ws + (102u << 20));   // 2 MB
  float*    wF    = (float*)   (ws + (104u << 20));   // 1 MB
  int*      idxF  = (int*)     (ws + (105u << 20));   // 1 MB

  // plane splits
  split_kernel<10, true ><<<2048, 256, 0, stream>>>(x,    xs,    524288);
  split_kernel<10, false><<<2048, 256, 0, stream>>>(w_q,  wqs,   524288);
  split_kernel<8,  false><<<1024, 256, 0, stream>>>(keys, keyss, 262144);

  // GEMM1: Q'' = split(x'' @ w_q''^T + b) : M=2048, N=2048, K'=3072
  mfma_gemm<true><<<dim3(QDIM / 128, BSZ / 128, 1), 256, 34816, stream>>>(
      xs, 3 * INDIM, 0, wqs, 3 * INDIM, 0, b_q,
      nullptr, 0, 0, Qs, 3 * INDIM);
  // GEMM2: S = Q'' @ keys''^T : 8 x (M=2048, N=512, K'=768)
  mfma_gemm<false><<<dim3(NKEYS / 128, BSZ / 128, NHT), 256, 32768, stream>>>(
      Qs, 3 * HALFD * NHT, 3 * HALFD, keyss, 3 * HALFD, (long)NKEYS * 3 * HALFD, nullptr,
      S, NHT * NKEYS, NKEYS, nullptr, 3 * HALFD);

  topk1_kernel<<<BSZ * NHT, 64, 0, stream>>>(S, sTop, iTop);
  topk2_kernel<<<BSZ * HEADS, 64, 0, stream>>>(sTop, iTop, wF, idxF);
  gather_kernel<<<BSZ, 256, 0, stream>>>(values, wF, idxF, out);
}